// Round 12
// baseline (154.038 us; speedup 1.0000x reference)
//
#include <hip/hip_runtime.h>
#include <hip/hip_fp8.h>

#define NV 4
#define NB 2048
#define ND 512
#define NN 8192
// sim = cos/TEMP, TEMP=0.5 -> scale 2.0

typedef int int8v __attribute__((ext_vector_type(8)));
typedef int int4v __attribute__((ext_vector_type(4)));
typedef float floatx4 __attribute__((ext_vector_type(4)));
#define SCALE1 0x7F7F7F7Fu  // E8M0 bytes 127 -> 2^0 = 1.0
#define NTILE 8256           // 128*129/2 upper-tri 64x64 tiles
#define NWAVE 3072           // 768 blocks x 4 waves (3 blocks/CU persistent)

// ---------------- normalize: x[N,D] f32 -> xn[N,D] fp8 e4m3 (unit rows) ----
__global__ __launch_bounds__(256) void normalize_k(const float* __restrict__ x,
                                                   unsigned char* __restrict__ xn,
                                                   float* __restrict__ sumexp,
                                                   float* __restrict__ out) {
  if (threadIdx.x < 4) sumexp[blockIdx.x * 4 + threadIdx.x] = 0.0f;
  if (blockIdx.x == 0 && threadIdx.x == 0) out[0] = 0.0f;

  const int row = blockIdx.x * 4 + (threadIdx.x >> 6);  // one wave per row
  const int l = threadIdx.x & 63;
  const float4* xr = (const float4*)(x + (size_t)row * ND);
  float4 v0 = xr[l * 2 + 0];
  float4 v1 = xr[l * 2 + 1];
  float ss = v0.x * v0.x + v0.y * v0.y + v0.z * v0.z + v0.w * v0.w +
             v1.x * v1.x + v1.y * v1.y + v1.z * v1.z + v1.w * v1.w;
#pragma unroll
  for (int off = 32; off > 0; off >>= 1) ss += __shfl_xor(ss, off, 64);
  const float inv = 1.0f / fmaxf(sqrtf(ss), 1e-8f);
  union { unsigned char b[8]; uint2 u; } pk;
  pk.b[0] = __hip_fp8_e4m3(v0.x * inv).__x;
  pk.b[1] = __hip_fp8_e4m3(v0.y * inv).__x;
  pk.b[2] = __hip_fp8_e4m3(v0.z * inv).__x;
  pk.b[3] = __hip_fp8_e4m3(v0.w * inv).__x;
  pk.b[4] = __hip_fp8_e4m3(v1.x * inv).__x;
  pk.b[5] = __hip_fp8_e4m3(v1.y * inv).__x;
  pk.b[6] = __hip_fp8_e4m3(v1.z * inv).__x;
  pk.b[7] = __hip_fp8_e4m3(v1.w * inv).__x;
  *(uint2*)(xn + (size_t)row * ND + l * 8) = pk.u;
}

// ---------------- fused sim GEMM + exp/mask epilogue -------------------------
// R12: PERSISTENT waves, ZERO LDS. Each wave grid-strides over upper-tri
// 64x64 tiles. Fragments for mfma_scale_f32_16x16x128_f8f6f4 are loaded
// DIRECTLY from global (L2-resident, 4 MB): lane l <- row (panel*16 + (l&15)),
// bytes q*32..+32 of the kt'th 128-B K-window — the exact layout the LDS path
// fed (verified absmax 0 since R5). No ds_read/ds_write/barriers at all.
// Rationale: R8-R11 pinned ~50 us across four K-loop structures; wave
// lifetime was dominated by prologue/epilogue latency amortized over only 4
// K-iters, with LDS round-trip + barrier lockstep keeping pipes sequential.
// Epilogue is wave-uniformly specialized: masked cols ((c-r)%2048==0) exist
// only in tiles with (ct-rt)%32==0 (1/32 of tiles); all other tiles run a
// branch-free exp+sum epilogue with no pos stores.
__global__ __launch_bounds__(256) void sim_k(const unsigned char* __restrict__ xn,
                                             float* __restrict__ sumexp,
                                             float* __restrict__ pos) {
  const int tid = threadIdx.x;
  const int l = tid & 63;
  const int m = l & 15, q = l >> 4;
  const int gw = blockIdx.x * 4 + (tid >> 6);  // persistent wave id 0..3071

  for (int tile = gw; tile < NTILE; tile += NWAVE) {
    // triangular decode over 128x128 tile grid: start(r) = r*128 - r(r-1)/2
    int rt = (int)((257.0f - sqrtf(66049.0f - 8.0f * (float)tile)) * 0.5f);
    rt = rt < 0 ? 0 : (rt > 127 ? 127 : rt);
    while (rt > 0 && (rt * 128 - rt * (rt - 1) / 2) > tile) --rt;
    while (rt < 127 && ((rt + 1) * 128 - (rt + 1) * rt / 2) <= tile) ++rt;
    const int ct = rt + (tile - (rt * 128 - rt * (rt - 1) / 2));
    const bool diag = (rt == ct);

    floatx4 acc[4][4] = {};

    // per-panel fragment base pointers: row (tile*64 + t*16 + m), byte q*32
    const unsigned char* pa[4];
    const unsigned char* pb[4];
#pragma unroll
    for (int t = 0; t < 4; ++t) {
      pa[t] = xn + (size_t)(rt * 64 + t * 16 + m) * ND + q * 32;
      pb[t] = xn + (size_t)(ct * 64 + t * 16 + m) * ND + q * 32;
    }

#pragma unroll 1  // rolled: 64 live frag regs max (full unroll would hoist
    for (int kt = 0; kt < 4; ++kt) {  // 256 regs of loads -> spill, cf. R5)
      int8v af0, af1, af2, af3, bf0, bf1, bf2, bf3;
      af0 = __builtin_shufflevector(*(const int4v*)(pa[0]),
                                    *(const int4v*)(pa[0] + 16), 0,1,2,3,4,5,6,7);
      af1 = __builtin_shufflevector(*(const int4v*)(pa[1]),
                                    *(const int4v*)(pa[1] + 16), 0,1,2,3,4,5,6,7);
      af2 = __builtin_shufflevector(*(const int4v*)(pa[2]),
                                    *(const int4v*)(pa[2] + 16), 0,1,2,3,4,5,6,7);
      af3 = __builtin_shufflevector(*(const int4v*)(pa[3]),
                                    *(const int4v*)(pa[3] + 16), 0,1,2,3,4,5,6,7);
      bf0 = __builtin_shufflevector(*(const int4v*)(pb[0]),
                                    *(const int4v*)(pb[0] + 16), 0,1,2,3,4,5,6,7);
      bf1 = __builtin_shufflevector(*(const int4v*)(pb[1]),
                                    *(const int4v*)(pb[1] + 16), 0,1,2,3,4,5,6,7);
      bf2 = __builtin_shufflevector(*(const int4v*)(pb[2]),
                                    *(const int4v*)(pb[2] + 16), 0,1,2,3,4,5,6,7);
      bf3 = __builtin_shufflevector(*(const int4v*)(pb[3]),
                                    *(const int4v*)(pb[3] + 16), 0,1,2,3,4,5,6,7);
#define MFMA_ROW(mt, afv)                                                     \
  acc[mt][0] = __builtin_amdgcn_mfma_scale_f32_16x16x128_f8f6f4(              \
      afv, bf0, acc[mt][0], 0, 0, 0, SCALE1, 0, SCALE1);                      \
  acc[mt][1] = __builtin_amdgcn_mfma_scale_f32_16x16x128_f8f6f4(              \
      afv, bf1, acc[mt][1], 0, 0, 0, SCALE1, 0, SCALE1);                      \
  acc[mt][2] = __builtin_amdgcn_mfma_scale_f32_16x16x128_f8f6f4(              \
      afv, bf2, acc[mt][2], 0, 0, 0, SCALE1, 0, SCALE1);                      \
  acc[mt][3] = __builtin_amdgcn_mfma_scale_f32_16x16x128_f8f6f4(              \
      afv, bf3, acc[mt][3], 0, 0, 0, SCALE1, 0, SCALE1)
      MFMA_ROW(0, af0);
      MFMA_ROW(1, af1);
      MFMA_ROW(2, af2);
      MFMA_ROW(3, af3);
#undef MFMA_ROW
#pragma unroll
      for (int t = 0; t < 4; ++t) { pa[t] += 128; pb[t] += 128; }
    }

    // ---- epilogue ----
    const int r0 = rt * 64;
    const int c0 = ct * 64;
    const bool masked = (((ct - rt) & 31) == 0);  // wave-uniform
    float cs[4] = {0.f, 0.f, 0.f, 0.f};
#pragma unroll
    for (int mt = 0; mt < 4; ++mt) {
      float rs[4] = {0.f, 0.f, 0.f, 0.f};
#pragma unroll
      for (int nt = 0; nt < 4; ++nt) {
#pragma unroll
        for (int reg = 0; reg < 4; ++reg) {
          const float e = __expf(acc[mt][nt][reg] * 2.0f);
          rs[reg] += e;
          cs[nt] += e;
        }
      }
      if (masked) {
        // diag elements live at nt==mt, lane cond m == q*4+reg: subtract from
        // sums (they are the positives, excluded from negatives) + store pos.
        const int reg = m - q * 4;
        if (reg >= 0 && reg < 4) {
          const float sv = acc[mt][mt][reg] * 2.0f;
          const float e = __expf(sv);
          rs[reg] -= e;
          cs[mt] -= e;
          const int r = r0 + mt * 16 + m;  // q*4+reg == m here
          const int c = c0 + mt * 16 + m;
          pos[r * NV + (c >> 11)] = sv;
          if (!diag) pos[c * NV + (r >> 11)] = sv;
        }
      }
#pragma unroll
      for (int off = 1; off < 16; off <<= 1) {
#pragma unroll
        for (int reg = 0; reg < 4; ++reg)
          rs[reg] += __shfl_xor(rs[reg], off, 64);
      }
      if (m < 4) atomicAdd(&sumexp[r0 + mt * 16 + q * 4 + m], rs[m]);
    }
    if (!diag) {
#pragma unroll
      for (int nt = 0; nt < 4; ++nt) {
        cs[nt] += __shfl_xor(cs[nt], 16, 64);
        cs[nt] += __shfl_xor(cs[nt], 32, 64);
      }
      if (q == 0) {
#pragma unroll
        for (int nt = 0; nt < 4; ++nt)
          atomicAdd(&sumexp[c0 + nt * 16 + m], cs[nt]);
      }
    }
  }
}

// ---------------- finalize: scalar loss -------------------------------------
__global__ __launch_bounds__(256) void finalize_k(
    const float* __restrict__ sumexp, const float* __restrict__ pos,
    float* __restrict__ out) {
  const int r = blockIdx.x * 256 + threadIdx.x;
  const float se = sumexp[r];
  const int i = r >> 11;
  float local = 0.0f;
#pragma unroll
  for (int j = 0; j < NV; ++j) {
    if (j == i) continue;
    const float p = pos[r * NV + j];
    local += logf(__expf(p) + se) - p;
  }
  local *= (1.0f / NB);
#pragma unroll
  for (int off = 32; off > 0; off >>= 1) local += __shfl_xor(local, off, 64);
  if ((threadIdx.x & 63) == 0) atomicAdd(out, local);
}

extern "C" void kernel_launch(void* const* d_in, const int* in_sizes, int n_in,
                              void* d_out, int out_size, void* d_ws,
                              size_t ws_size, hipStream_t stream) {
  const float* x = (const float*)d_in[0];
  float* out = (float*)d_out;
  char* ws = (char*)d_ws;
  unsigned char* xn = (unsigned char*)ws;                 // 4 MB fp8
  float* sumexp = (float*)(ws + (size_t)NN * ND);         // 32 KB
  float* pos = (float*)(ws + (size_t)NN * ND + NN * 4);   // 128 KB

  normalize_k<<<NN / 4, 256, 0, stream>>>(x, xn, sumexp, out);
  sim_k<<<NWAVE / 4, 256, 0, stream>>>(xn, sumexp, pos);
  finalize_k<<<NN / 256, 256, 0, stream>>>(sumexp, pos, out);
}